// Round 7
// baseline (105.895 us; speedup 1.0000x reference)
//
#include <hip/hip_runtime.h>
#include <math.h>

#define NGAUSS 2000
#define IMW 128
#define IMH 128
#define NPIX (IMW*IMH)
#define PSTRIDE 12
#define NSEG 32
#define PERSEG ((NGAUSS + NSEG - 1) / NSEG)   // 63
#define PXT 4                                  // pixels per thread (same row)
#define NGROUP (NPIX/(256*PXT))                // 16 pixel-groups

// ---------------- fused prep + stable rank sort + scatter (+ counter reset) ----
// One wave per gaussian. Param layout (per gaussian, 3 x float4):
//   [0] = { m2x, m2y, s_cull, q0s }   s_cull = lambda_min(Q) * log2(e)
//   [1] = { q1s, q2s, c0,    cr  }   qXs pre-scaled by -log2(e) for exp2
//   [2] = { cg,  cb,  depth, 0   }
__global__ __launch_bounds__(64) void preprank_kernel(
    const float* __restrict__ means3D, const float* __restrict__ covs3d,
    const float* __restrict__ colors, const float* __restrict__ opac,
    const float* __restrict__ Km, const float* __restrict__ Rm,
    const float* __restrict__ tv, float* __restrict__ sorted,
    unsigned int* __restrict__ counters)
{
    int i = blockIdx.x;
    int lane = threadIdx.x;
    if (i == 0 && lane < NGROUP) counters[lane] = 0;   // reset for this call

    float R0 = Rm[0], R1 = Rm[1], R2 = Rm[2];
    float R3 = Rm[3], R4 = Rm[4], R5 = Rm[5];
    float R6 = Rm[6], R7 = Rm[7], R8 = Rm[8];
    float t0 = tv[0], t1v = tv[1], t2 = tv[2];

    // ---- rank: recompute depth_j inline (identical expression for i and j) ----
    float mx = means3D[3*i+0], my = means3D[3*i+1], mz = means3D[3*i+2];
    float di = fmaxf(R6*mx + R7*my + R8*mz + t2, 1.0f);
    int rank = 0;
    for (int j = lane; j < NGAUSS; j += 64) {
        float jx = means3D[3*j+0], jy = means3D[3*j+1], jz = means3D[3*j+2];
        float dj = fmaxf(R6*jx + R7*jy + R8*jz + t2, 1.0f);
        bool lt = (j != i) && ((dj < di) || (dj == di && j < i));  // stable, self-safe
        rank += lt ? 1 : 0;
    }
    #pragma unroll
    for (int o = 32; o > 0; o >>= 1) rank += __shfl_down(rank, o, 64);
    rank = __shfl(rank, 0, 64);

    // ---- prep (redundant on all lanes) ----
    float camx = R0*mx + R1*my + R2*mz + t0;
    float camy = R3*mx + R4*my + R5*mz + t1v;
    float camz = R6*mx + R7*my + R8*mz + t2;
    float depth = fmaxf(camz, 1.0f);
    bool valid = (depth > 1.0f) && (depth < 50.0f);

    float fx = Km[0], cx = Km[2], fy = Km[4], cy = Km[5];
    float invz = 1.0f / camz;
    float m2x = (fx*camx + cx*camz) * invz;
    float m2y = (fy*camy + cy*camz) * invz;
    float J00 = fx*invz, J02 = -fx*camx*invz*invz;
    float J11 = fy*invz, J12 = -fy*camy*invz*invz;

    float S0 = covs3d[9*i+0], S1 = covs3d[9*i+1], S2 = covs3d[9*i+2];
    float S3 = covs3d[9*i+3], S4 = covs3d[9*i+4], S5 = covs3d[9*i+5];
    float S6 = covs3d[9*i+6], S7 = covs3d[9*i+7], S8 = covs3d[9*i+8];

    float RS0 = R0*S0 + R1*S3 + R2*S6;
    float RS1 = R0*S1 + R1*S4 + R2*S7;
    float RS2 = R0*S2 + R1*S5 + R2*S8;
    float RS3 = R3*S0 + R4*S3 + R5*S6;
    float RS4 = R3*S1 + R4*S4 + R5*S7;
    float RS5 = R3*S2 + R4*S5 + R5*S8;
    float RS6 = R6*S0 + R7*S3 + R8*S6;
    float RS7 = R6*S1 + R7*S4 + R8*S7;
    float RS8 = R6*S2 + R7*S5 + R8*S8;

    float Sc0 = RS0*R0 + RS1*R1 + RS2*R2;
    float Sc1 = RS0*R3 + RS1*R4 + RS2*R5;
    float Sc2 = RS0*R6 + RS1*R7 + RS2*R8;
    float Sc3 = RS3*R0 + RS4*R1 + RS5*R2;
    float Sc4 = RS3*R3 + RS4*R4 + RS5*R5;
    float Sc5 = RS3*R6 + RS4*R7 + RS5*R8;
    float Sc6 = RS6*R0 + RS7*R1 + RS8*R2;
    float Sc7 = RS6*R3 + RS7*R4 + RS8*R5;
    float Sc8 = RS6*R6 + RS7*R7 + RS8*R8;

    float A00 = J00*Sc0 + J02*Sc6;
    float A01 = J00*Sc1 + J02*Sc7;
    float A02 = J00*Sc2 + J02*Sc8;
    float A10 = J11*Sc3 + J12*Sc6;
    float A11 = J11*Sc4 + J12*Sc7;
    float A12 = J11*Sc5 + J12*Sc8;

    float a = A00*J00 + A02*J02 + 1e-4f;
    float b = A01*J11 + A02*J12;
    float c = A10*J00 + A12*J02;
    float d = A11*J11 + A12*J12 + 1e-4f;

    float det = a*d - b*c;
    float invdet = 1.0f / det;
    float q0u = d*invdet;
    float q1u = -(b + c)*invdet;
    float q2u = a*invdet;
    // smallest eigenvalue of [[q0u, q1u/2],[q1u/2, q2u]] for conservative cull
    float mh = 0.5f*(q0u + q2u);
    float dh = 0.5f*(q0u - q2u);
    float oh = 0.5f*q1u;
    float lmin = mh - sqrtf(dh*dh + oh*oh);
    const float L2E = 1.4426950408889634f;
    float s_cull = lmin * L2E;
    float q0 = -q0u * L2E;
    float q1 = -q1u * L2E;
    float q2 = -q2u * L2E;
    float c0 = opac[i] * 0.15915494309189535f / sqrtf(det);
    if (!valid) { m2x = 0.f; m2y = 0.f; q0 = 0.f; q1 = 0.f; q2 = 0.f; c0 = 0.f; s_cull = 3.0e38f; }

    float cr = colors[3*i+0], cg = colors[3*i+1], cb = colors[3*i+2];
    if (lane < 3) {
        float4 v = (lane == 0) ? make_float4(m2x, m2y, s_cull, q0)
                 : (lane == 1) ? make_float4(q1, q2, c0, cr)
                               : make_float4(cg, cb, depth, 0.f);
        ((float4*)(sorted + (size_t)rank*PSTRIDE))[lane] = v;
    }
}

// ---------------- render + last-block combine ----------------
// Reference semantics: weight[0] = a_0;  weight[n>=1] = a_n*(1-a_n)*prod_{k<n}(1-a_k)
__global__ __launch_bounds__(256) void render_kernel(
    const float* __restrict__ sorted, float4* __restrict__ segOut,
    float* __restrict__ out, unsigned int* __restrict__ counters)
{
    __shared__ float4 sp[PERSEG * 3];
    __shared__ int isLast;
    int tid = threadIdx.x;
    int seg = blockIdx.y;
    int base = seg * PERSEG;
    int cnt = NGAUSS - base; if (cnt > PERSEG) cnt = PERSEG; if (cnt < 0) cnt = 0;

    const float4* src = (const float4*)(sorted + (size_t)base*PSTRIDE);
    if (tid < cnt*3) sp[tid] = src[tid];
    __syncthreads();

    int p0 = (blockIdx.x*256 + tid) * PXT;
    float py = (float)(p0 >> 7);
    float px0 = (float)(p0 & (IMW-1));
    // wave-uniform 2-row span for culling
    int wavebase = (blockIdx.x*256 + (tid & ~63)) * PXT;
    float ry0 = (float)(wavebase >> 7);      // rows ry0, ry0+1; cols 0..127

    float Cr[PXT], Cg[PXT], Cb[PXT], T[PXT];
    #pragma unroll
    for (int j = 0; j < PXT; ++j) { Cr[j]=0.f; Cg[j]=0.f; Cb[j]=0.f; T[j]=1.f; }

    int n0 = 0;
    if (seg == 0) {
        // globally-first sorted gaussian: weight = alpha (no self (1-alpha) factor)
        float4 a0 = sp[0], a1 = sp[1], a2 = sp[2];
        float dy = py - a0.y;
        float u1 = a1.x * dy;
        float u2 = (a1.y * dy) * dy;
        #pragma unroll
        for (int j = 0; j < PXT; ++j) {
            float dx = px0 + (float)j - a0.x;
            float e = fmaf(fmaf(a0.w, dx, u1), dx, u2);
            float al = a1.z * exp2f(e);
            Cr[j] = fmaf(al, a1.w, Cr[j]);
            Cg[j] = fmaf(al, a2.x, Cg[j]);
            Cb[j] = fmaf(al, a2.y, Cb[j]);
            T[j] -= al;
        }
        n0 = 1;
    }
    for (int n = n0; n < cnt; ++n) {
        float4 a0 = sp[n*3+0];
        // conservative wave-uniform cull: min dist^2 from mean to the
        // wave's 2-row x 128-col rectangle, scaled by lambda_min*log2e
        float dxm = fmaxf(0.f, fmaxf(-a0.x, a0.x - 127.f));
        float dym = fmaxf(0.f, fmaxf(ry0 - a0.y, a0.y - (ry0 + 1.f)));
        if (a0.z * fmaf(dxm, dxm, dym*dym) > 24.f) continue;  // alpha < c0*2^-24

        float4 a1 = sp[n*3+1], a2 = sp[n*3+2];
        float dy = py - a0.y;
        float u1 = a1.x * dy;
        float u2 = (a1.y * dy) * dy;
        #pragma unroll
        for (int j = 0; j < PXT; ++j) {
            float dx = px0 + (float)j - a0.x;
            float e = fmaf(fmaf(a0.w, dx, u1), dx, u2);
            float g = exp2f(e);
            float al = a1.z * g;          // alpha
            float w = T[j] * al;          // T*alpha
            float f = fmaf(-al, w, w);    // T*alpha*(1-alpha)
            Cr[j] = fmaf(f, a1.w, Cr[j]);
            Cg[j] = fmaf(f, a2.x, Cg[j]);
            Cb[j] = fmaf(f, a2.y, Cb[j]);
            T[j] -= w;                    // T *= (1-alpha)
        }
    }
    size_t ob = (size_t)seg*NPIX + p0;
    #pragma unroll
    for (int j = 0; j < PXT; ++j)
        segOut[ob + j] = make_float4(Cr[j], Cg[j], Cb[j], T[j]);

    // ---- last finishing block for this pixel-group composites all segments ----
    __threadfence();                       // make this thread's stores visible
    __syncthreads();                       // all threads' fences done
    if (tid == 0) {
        unsigned int old = atomicAdd(&counters[blockIdx.x], 1u);
        isLast = (old == NSEG - 1) ? 1 : 0;
    }
    __syncthreads();
    if (isLast) {
        __threadfence();                   // acquire: see all blocks' segOut
        float cR[PXT], cG[PXT], cB[PXT], tA[PXT];
        #pragma unroll
        for (int j = 0; j < PXT; ++j) { cR[j]=0.f; cG[j]=0.f; cB[j]=0.f; tA[j]=1.f; }
        for (int s = 0; s < NSEG; ++s) {
            #pragma unroll
            for (int j = 0; j < PXT; ++j) {
                float4 v = segOut[(size_t)s*NPIX + p0 + j];
                cR[j] = fmaf(tA[j], v.x, cR[j]);
                cG[j] = fmaf(tA[j], v.y, cG[j]);
                cB[j] = fmaf(tA[j], v.z, cB[j]);
                tA[j] *= v.w;
            }
        }
        #pragma unroll
        for (int j = 0; j < PXT; ++j) {
            int p = p0 + j;
            out[3*p+0] = cR[j]; out[3*p+1] = cG[j]; out[3*p+2] = cB[j];
        }
    }
}

extern "C" void kernel_launch(void* const* d_in, const int* in_sizes, int n_in,
                              void* d_out, int out_size, void* d_ws, size_t ws_size,
                              hipStream_t stream)
{
    const float* means3D = (const float*)d_in[0];
    const float* covs3d  = (const float*)d_in[1];
    const float* colors  = (const float*)d_in[2];
    const float* opac    = (const float*)d_in[3];
    const float* Km      = (const float*)d_in[4];
    const float* Rm      = (const float*)d_in[5];
    const float* tv      = (const float*)d_in[6];

    float* ws     = (float*)d_ws;
    float* sorted = ws;                       // NGAUSS*12 floats = 96 KB
    float* segOut = ws + 24000;               // NSEG*NPIX*4 floats = 8.4 MB
    unsigned int* counters =
        (unsigned int*)(ws + 24000 + (size_t)NSEG*NPIX*4);  // 16 uints, 16B-aligned

    preprank_kernel<<<NGAUSS, 64, 0, stream>>>(
        means3D, covs3d, colors, opac, Km, Rm, tv, sorted, counters);
    dim3 rg(NGROUP, NSEG);
    render_kernel<<<rg, 256, 0, stream>>>(
        sorted, (float4*)segOut, (float*)d_out, counters);
}

// Round 8
// 80.920 us; speedup vs baseline: 1.3086x; 1.3086x over previous
//
#include <hip/hip_runtime.h>
#include <math.h>

#define NGAUSS 2000
#define IMW 128
#define IMH 128
#define NPIX (IMW*IMH)
#define PSTRIDE 12
#define CHUNK 512                 // gaussians staged per round
#define NROUND ((NGAUSS + CHUNK - 1) / CHUNK)   // 4

// ---------------- fused prep + stable rank sort + scatter ----------------
// One wave per gaussian. Param layout (per gaussian, 3 x float4):
//   [0] = { m2x, m2y, s_cull, q0s }   s_cull = lambda_min(Q) * log2(e)
//   [1] = { q1s, q2s, c0,    cr  }   qXs pre-scaled by -log2(e) for exp2
//   [2] = { cg,  cb,  depth, 0   }
__global__ __launch_bounds__(64) void preprank_kernel(
    const float* __restrict__ means3D, const float* __restrict__ covs3d,
    const float* __restrict__ colors, const float* __restrict__ opac,
    const float* __restrict__ Km, const float* __restrict__ Rm,
    const float* __restrict__ tv, float* __restrict__ sorted)
{
    int i = blockIdx.x;
    int lane = threadIdx.x;

    float R0 = Rm[0], R1 = Rm[1], R2 = Rm[2];
    float R3 = Rm[3], R4 = Rm[4], R5 = Rm[5];
    float R6 = Rm[6], R7 = Rm[7], R8 = Rm[8];
    float t0 = tv[0], t1v = tv[1], t2 = tv[2];

    // ---- rank: recompute depth_j inline (identical expression for i and j) ----
    float mx = means3D[3*i+0], my = means3D[3*i+1], mz = means3D[3*i+2];
    float di = fmaxf(R6*mx + R7*my + R8*mz + t2, 1.0f);
    int rank = 0;
    for (int j = lane; j < NGAUSS; j += 64) {
        float jx = means3D[3*j+0], jy = means3D[3*j+1], jz = means3D[3*j+2];
        float dj = fmaxf(R6*jx + R7*jy + R8*jz + t2, 1.0f);
        bool lt = (j != i) && ((dj < di) || (dj == di && j < i));  // stable, self-safe
        rank += lt ? 1 : 0;
    }
    #pragma unroll
    for (int o = 32; o > 0; o >>= 1) rank += __shfl_down(rank, o, 64);
    rank = __shfl(rank, 0, 64);

    // ---- prep (redundant on all lanes) ----
    float camx = R0*mx + R1*my + R2*mz + t0;
    float camy = R3*mx + R4*my + R5*mz + t1v;
    float camz = R6*mx + R7*my + R8*mz + t2;
    float depth = fmaxf(camz, 1.0f);
    bool valid = (depth > 1.0f) && (depth < 50.0f);

    float fx = Km[0], cx = Km[2], fy = Km[4], cy = Km[5];
    float invz = 1.0f / camz;
    float m2x = (fx*camx + cx*camz) * invz;
    float m2y = (fy*camy + cy*camz) * invz;
    float J00 = fx*invz, J02 = -fx*camx*invz*invz;
    float J11 = fy*invz, J12 = -fy*camy*invz*invz;

    float S0 = covs3d[9*i+0], S1 = covs3d[9*i+1], S2 = covs3d[9*i+2];
    float S3 = covs3d[9*i+3], S4 = covs3d[9*i+4], S5 = covs3d[9*i+5];
    float S6 = covs3d[9*i+6], S7 = covs3d[9*i+7], S8 = covs3d[9*i+8];

    float RS0 = R0*S0 + R1*S3 + R2*S6;
    float RS1 = R0*S1 + R1*S4 + R2*S7;
    float RS2 = R0*S2 + R1*S5 + R2*S8;
    float RS3 = R3*S0 + R4*S3 + R5*S6;
    float RS4 = R3*S1 + R4*S4 + R5*S7;
    float RS5 = R3*S2 + R4*S5 + R5*S8;
    float RS6 = R6*S0 + R7*S3 + R8*S6;
    float RS7 = R6*S1 + R7*S4 + R8*S7;
    float RS8 = R6*S2 + R7*S5 + R8*S8;

    float Sc0 = RS0*R0 + RS1*R1 + RS2*R2;
    float Sc1 = RS0*R3 + RS1*R4 + RS2*R5;
    float Sc2 = RS0*R6 + RS1*R7 + RS2*R8;
    float Sc3 = RS3*R0 + RS4*R1 + RS5*R2;
    float Sc4 = RS3*R3 + RS4*R4 + RS5*R5;
    float Sc5 = RS3*R6 + RS4*R7 + RS5*R8;
    float Sc6 = RS6*R0 + RS7*R1 + RS8*R2;
    float Sc7 = RS6*R3 + RS7*R4 + RS8*R5;
    float Sc8 = RS6*R6 + RS7*R7 + RS8*R8;

    float A00 = J00*Sc0 + J02*Sc6;
    float A01 = J00*Sc1 + J02*Sc7;
    float A02 = J00*Sc2 + J02*Sc8;
    float A10 = J11*Sc3 + J12*Sc6;
    float A11 = J11*Sc4 + J12*Sc7;
    float A12 = J11*Sc5 + J12*Sc8;

    float a = A00*J00 + A02*J02 + 1e-4f;
    float b = A01*J11 + A02*J12;
    float c = A10*J00 + A12*J02;
    float d = A11*J11 + A12*J12 + 1e-4f;

    float det = a*d - b*c;
    float invdet = 1.0f / det;
    float q0u = d*invdet;
    float q1u = -(b + c)*invdet;
    float q2u = a*invdet;
    // smallest eigenvalue of [[q0u, q1u/2],[q1u/2, q2u]] for conservative cull
    float mh = 0.5f*(q0u + q2u);
    float dh = 0.5f*(q0u - q2u);
    float oh = 0.5f*q1u;
    float lmin = mh - sqrtf(dh*dh + oh*oh);
    const float L2E = 1.4426950408889634f;
    float s_cull = lmin * L2E;
    float q0 = -q0u * L2E;
    float q1 = -q1u * L2E;
    float q2 = -q2u * L2E;
    float c0 = opac[i] * 0.15915494309189535f / sqrtf(det);
    if (!valid) { m2x = 0.f; m2y = 0.f; q0 = 0.f; q1 = 0.f; q2 = 0.f; c0 = 0.f; s_cull = 3.0e38f; }

    float cr = colors[3*i+0], cg = colors[3*i+1], cb = colors[3*i+2];
    if (lane < 3) {
        float4 v = (lane == 0) ? make_float4(m2x, m2y, s_cull, q0)
                 : (lane == 1) ? make_float4(q1, q2, c0, cr)
                               : make_float4(cg, cb, depth, 0.f);
        ((float4*)(sorted + (size_t)rank*PSTRIDE))[lane] = v;
    }
}

// ---------------- monolithic render: 1 wave = 64 px of one row, all gaussians ----
// Reference semantics: weight[0] = a_0;  weight[n>=1] = a_n*(1-a_n)*prod_{k<n}(1-a_k)
// Ballot-compaction: per 64-gaussian chunk, lane t tests gaussian t against the
// wave's 64x1 pixel rect; survivors walked in ascending order via the ballot mask
// with wave-uniform broadcast LDS reads. Depth order preserved.
__global__ __launch_bounds__(64) void render_mono(
    const float* __restrict__ sorted, float* __restrict__ out)
{
    __shared__ float4 sp[CHUNK * 3];   // 24 KB
    int tid = threadIdx.x;
    int bid = blockIdx.x;
    int p = bid * 64 + tid;            // all 64 px of a wave are in one row
    float px = (float)(p & (IMW-1));
    float py = (float)(p >> 7);
    float ry = (float)((bid * 64) >> 7);          // wave's row (uniform)
    float x0 = (float)((bid & 1) * 64);           // wave's x-span [x0, x0+63]
    float x1 = x0 + 63.0f;

    float Cr = 0.f, Cg = 0.f, Cb = 0.f, T = 1.f;

    for (int r = 0; r < NROUND; ++r) {
        int gbase = r * CHUNK;
        int cnt = NGAUSS - gbase; if (cnt > CHUNK) cnt = CHUNK;
        __syncthreads();
        const float4* src = (const float4*)(sorted + (size_t)gbase * PSTRIDE);
        for (int k = tid; k < cnt * 3; k += 64) sp[k] = src[k];
        __syncthreads();

        for (int cb = 0; cb < cnt; cb += 64) {
            int g = cb + tid;
            float4 cq = sp[g * 3];                 // per-lane cull quad (48B stride)
            bool keep = false;
            if (g < cnt) {
                float dxm = fmaxf(0.f, fmaxf(x0 - cq.x, cq.x - x1));
                float dym = fmaxf(0.f, fmaxf(ry - cq.y, cq.y - ry));
                keep = cq.z * fmaf(dxm, dxm, dym * dym) <= 24.f;  // alpha >= c0*2^-24
            }
            unsigned long long mask = __ballot(keep);
            while (mask) {
                int b = __builtin_ctzll(mask);
                mask &= mask - 1;
                int n = cb + b;
                float4 a0 = sp[n*3+0], a1 = sp[n*3+1], a2 = sp[n*3+2]; // broadcast
                int gn = gbase + n;
                float dy = py - a0.y;
                float u1 = a1.x * dy;
                float u2 = (a1.y * dy) * dy;
                float dx = px - a0.x;
                float e = fmaf(fmaf(a0.w, dx, u1), dx, u2);
                float al = a1.z * exp2f(e);        // alpha
                float w = T * al;                  // T*alpha
                float sel = (gn == 0) ? 0.f : al;  // first sorted gaussian: no self factor
                float f = fmaf(-sel, w, w);        // T*alpha*(1-alpha)  (or T*alpha for n=0)
                Cr = fmaf(f, a1.w, Cr);
                Cg = fmaf(f, a2.x, Cg);
                Cb = fmaf(f, a2.y, Cb);
                T -= w;                            // T *= (1-alpha)
            }
        }
    }
    out[3*p+0] = Cr; out[3*p+1] = Cg; out[3*p+2] = Cb;
}

extern "C" void kernel_launch(void* const* d_in, const int* in_sizes, int n_in,
                              void* d_out, int out_size, void* d_ws, size_t ws_size,
                              hipStream_t stream)
{
    const float* means3D = (const float*)d_in[0];
    const float* covs3d  = (const float*)d_in[1];
    const float* colors  = (const float*)d_in[2];
    const float* opac    = (const float*)d_in[3];
    const float* Km      = (const float*)d_in[4];
    const float* Rm      = (const float*)d_in[5];
    const float* tv      = (const float*)d_in[6];

    float* sorted = (float*)d_ws;   // NGAUSS*12 floats = 96 KB

    preprank_kernel<<<NGAUSS, 64, 0, stream>>>(
        means3D, covs3d, colors, opac, Km, Rm, tv, sorted);
    render_mono<<<NPIX/64, 64, 0, stream>>>(sorted, (float*)d_out);
}

// Round 9
// 26.968 us; speedup vs baseline: 3.9267x; 3.0006x over previous
//
#include <hip/hip_runtime.h>
#include <math.h>

#define NGAUSS 2000
#define IMW 128
#define IMH 128
#define NPIX (IMW*IMH)
#define PSTRIDE 12
#define NW 16                     // waves per render block
#define SEGSZ ((NGAUSS + NW - 1) / NW)   // 125 gaussians per wave-segment

__device__ inline float rdlane(float x, int l) {
    return __uint_as_float(__builtin_amdgcn_readlane(__float_as_uint(x), l));
}

// ---------------- fused prep + stable rank sort + scatter ----------------
// One wave per gaussian. Param layout (per gaussian, 3 x float4):
//   [0] = { m2x, m2y, s_cull, q0s }   s_cull = lambda_min(Q) * log2(e)
//   [1] = { q1s, q2s, c0,    cr  }   qXs pre-scaled by -log2(e) for exp2
//   [2] = { cg,  cb,  depth, 0   }
__global__ __launch_bounds__(64) void preprank_kernel(
    const float* __restrict__ means3D, const float* __restrict__ covs3d,
    const float* __restrict__ colors, const float* __restrict__ opac,
    const float* __restrict__ Km, const float* __restrict__ Rm,
    const float* __restrict__ tv, float* __restrict__ sorted)
{
    int i = blockIdx.x;
    int lane = threadIdx.x;

    float R0 = Rm[0], R1 = Rm[1], R2 = Rm[2];
    float R3 = Rm[3], R4 = Rm[4], R5 = Rm[5];
    float R6 = Rm[6], R7 = Rm[7], R8 = Rm[8];
    float t0 = tv[0], t1v = tv[1], t2 = tv[2];

    // ---- rank: recompute depth_j inline (identical expression for i and j) ----
    float mx = means3D[3*i+0], my = means3D[3*i+1], mz = means3D[3*i+2];
    float di = fmaxf(R6*mx + R7*my + R8*mz + t2, 1.0f);
    int rank = 0;
    for (int j = lane; j < NGAUSS; j += 64) {
        float jx = means3D[3*j+0], jy = means3D[3*j+1], jz = means3D[3*j+2];
        float dj = fmaxf(R6*jx + R7*jy + R8*jz + t2, 1.0f);
        bool lt = (j != i) && ((dj < di) || (dj == di && j < i));  // stable, self-safe
        rank += lt ? 1 : 0;
    }
    #pragma unroll
    for (int o = 32; o > 0; o >>= 1) rank += __shfl_down(rank, o, 64);
    rank = __shfl(rank, 0, 64);

    // ---- prep (redundant on all lanes) ----
    float camx = R0*mx + R1*my + R2*mz + t0;
    float camy = R3*mx + R4*my + R5*mz + t1v;
    float camz = R6*mx + R7*my + R8*mz + t2;
    float depth = fmaxf(camz, 1.0f);
    bool valid = (depth > 1.0f) && (depth < 50.0f);

    float fx = Km[0], cx = Km[2], fy = Km[4], cy = Km[5];
    float invz = 1.0f / camz;
    float m2x = (fx*camx + cx*camz) * invz;
    float m2y = (fy*camy + cy*camz) * invz;
    float J00 = fx*invz, J02 = -fx*camx*invz*invz;
    float J11 = fy*invz, J12 = -fy*camy*invz*invz;

    float S0 = covs3d[9*i+0], S1 = covs3d[9*i+1], S2 = covs3d[9*i+2];
    float S3 = covs3d[9*i+3], S4 = covs3d[9*i+4], S5 = covs3d[9*i+5];
    float S6 = covs3d[9*i+6], S7 = covs3d[9*i+7], S8 = covs3d[9*i+8];

    float RS0 = R0*S0 + R1*S3 + R2*S6;
    float RS1 = R0*S1 + R1*S4 + R2*S7;
    float RS2 = R0*S2 + R1*S5 + R2*S8;
    float RS3 = R3*S0 + R4*S3 + R5*S6;
    float RS4 = R3*S1 + R4*S4 + R5*S7;
    float RS5 = R3*S2 + R4*S5 + R5*S8;
    float RS6 = R6*S0 + R7*S3 + R8*S6;
    float RS7 = R6*S1 + R7*S4 + R8*S7;
    float RS8 = R6*S2 + R7*S5 + R8*S8;

    float Sc0 = RS0*R0 + RS1*R1 + RS2*R2;
    float Sc1 = RS0*R3 + RS1*R4 + RS2*R5;
    float Sc2 = RS0*R6 + RS1*R7 + RS2*R8;
    float Sc3 = RS3*R0 + RS4*R1 + RS5*R2;
    float Sc4 = RS3*R3 + RS4*R4 + RS5*R5;
    float Sc5 = RS3*R6 + RS4*R7 + RS5*R8;
    float Sc6 = RS6*R0 + RS7*R1 + RS8*R2;
    float Sc7 = RS6*R3 + RS7*R4 + RS8*R5;
    float Sc8 = RS6*R6 + RS7*R7 + RS8*R8;

    float A00 = J00*Sc0 + J02*Sc6;
    float A01 = J00*Sc1 + J02*Sc7;
    float A02 = J00*Sc2 + J02*Sc8;
    float A10 = J11*Sc3 + J12*Sc6;
    float A11 = J11*Sc4 + J12*Sc7;
    float A12 = J11*Sc5 + J12*Sc8;

    float a = A00*J00 + A02*J02 + 1e-4f;
    float b = A01*J11 + A02*J12;
    float c = A10*J00 + A12*J02;
    float d = A11*J11 + A12*J12 + 1e-4f;

    float det = a*d - b*c;
    float invdet = 1.0f / det;
    float q0u = d*invdet;
    float q1u = -(b + c)*invdet;
    float q2u = a*invdet;
    // smallest eigenvalue of [[q0u, q1u/2],[q1u/2, q2u]] for conservative cull
    float mh = 0.5f*(q0u + q2u);
    float dh = 0.5f*(q0u - q2u);
    float oh = 0.5f*q1u;
    float lmin = mh - sqrtf(dh*dh + oh*oh);
    const float L2E = 1.4426950408889634f;
    float s_cull = lmin * L2E;
    float q0 = -q0u * L2E;
    float q1 = -q1u * L2E;
    float q2 = -q2u * L2E;
    float c0 = opac[i] * 0.15915494309189535f / sqrtf(det);
    if (!valid) { m2x = 0.f; m2y = 0.f; q0 = 0.f; q1 = 0.f; q2 = 0.f; c0 = 0.f; s_cull = 3.0e38f; }

    float cr = colors[3*i+0], cg = colors[3*i+1], cb = colors[3*i+2];
    if (lane < 3) {
        float4 v = (lane == 0) ? make_float4(m2x, m2y, s_cull, q0)
                 : (lane == 1) ? make_float4(q1, q2, c0, cr)
                               : make_float4(cg, cb, depth, 0.f);
        ((float4*)(sorted + (size_t)rank*PSTRIDE))[lane] = v;
    }
}

// ---------------- fused render: block = 64x1 px tile, 16 waves split depth ----
// Wave w handles sorted ranks [w*SEGSZ, (w+1)*SEGSZ) for the tile's 64 pixels
// (1 px per lane). Ballot-cull per 64-gaussian chunk (SoA stride-1 LDS reads),
// survivors broadcast via v_readlane (VALU pipe, LDS stays idle). Partials
// combined in-LDS in segment (depth) order by wave 0.
// Reference semantics: weight[0]=a_0; weight[n>=1]=a_n*(1-a_n)*prod_{k<n}(1-a_k)
__global__ __launch_bounds__(1024) void render_fused(
    const float* __restrict__ sorted, float* __restrict__ out)
{
    extern __shared__ char ldsbuf[];
    float*  mxA  = (float*)ldsbuf;                 // [2048]
    float*  myA  = mxA + 2048;
    float*  sA   = myA + 2048;
    float*  q0A  = sA + 2048;
    float4* sp2  = (float4*)(q0A + 2048);          // [2000*2]
    float4* pOut = sp2 + 2*NGAUSS;                 // [NW*64]

    int tid  = threadIdx.x;
    int lane = tid & 63;
    int w    = tid >> 6;
    int bid  = blockIdx.x;
    int row  = bid >> 1;
    int xoff = (bid & 1) * 64;

    // ---- stage all params once (coalesced) ----
    for (int g = tid; g < NGAUSS; g += 1024) {
        const float4* src = (const float4*)(sorted + (size_t)g*PSTRIDE);
        float4 v0 = src[0], v1 = src[1], v2 = src[2];
        mxA[g] = v0.x; myA[g] = v0.y; sA[g] = v0.z; q0A[g] = v0.w;
        sp2[g*2] = v1; sp2[g*2+1] = v2;
    }
    __syncthreads();

    float px = (float)(xoff + lane);
    float py = (float)row;
    float x0 = (float)xoff, x1 = x0 + 63.0f;

    float Cr = 0.f, Cg = 0.f, Cb = 0.f, T = 1.f;

    int segBase = w * SEGSZ;
    int segEnd  = segBase + SEGSZ; if (segEnd > NGAUSS) segEnd = NGAUSS;

    for (int cb = segBase; cb < segEnd; cb += 64) {
        int g = cb + lane;
        float cmx = 0.f, cmy = 0.f, cq0 = 0.f;
        bool keep = false;
        if (g < segEnd) {
            cmx = mxA[g]; cmy = myA[g]; cq0 = q0A[g];
            float cs = sA[g];
            float dxm = fmaxf(0.f, fmaxf(x0 - cmx, cmx - x1));
            float dym = fabsf(py - cmy);
            keep = cs * fmaf(dxm, dxm, dym*dym) <= 24.f;   // alpha >= c0*2^-24
        }
        float4 v1 = make_float4(0.f,0.f,0.f,0.f), v2 = v1;
        if (keep) { v1 = sp2[g*2]; v2 = sp2[g*2+1]; }
        unsigned long long mask = __ballot(keep);
        while (mask) {
            int b = __builtin_ctzll(mask);
            mask &= mask - 1;
            int gn = cb + b;
            float gmx = rdlane(cmx, b), gmy = rdlane(cmy, b), gq0 = rdlane(cq0, b);
            float gq1 = rdlane(v1.x, b), gq2 = rdlane(v1.y, b), gc0 = rdlane(v1.z, b);
            float gcr = rdlane(v1.w, b), gcg = rdlane(v2.x, b), gcb = rdlane(v2.y, b);
            float dy = py - gmy;
            float u2 = fmaf(gq1, dy, 0.f);          // q1*dy  (u1)
            float dx = px - gmx;
            float e  = fmaf(fmaf(gq0, dx, u2), dx, (gq2*dy)*dy);
            float al = gc0 * exp2f(e);               // alpha
            float wgt = T * al;                      // T*alpha
            float sel = (gn == 0) ? 0.f : al;        // rank-0: weight = alpha exactly
            float f = fmaf(-sel, wgt, wgt);          // T*alpha*(1-alpha)
            Cr = fmaf(f, gcr, Cr);
            Cg = fmaf(f, gcg, Cg);
            Cb = fmaf(f, gcb, Cb);
            T -= wgt;                                // T *= (1-alpha)
        }
    }

    pOut[w*64 + lane] = make_float4(Cr, Cg, Cb, T);
    __syncthreads();

    // ---- wave 0 composites the 16 depth-ordered partials for its 64 px ----
    if (tid < 64) {
        float cR = 0.f, cG = 0.f, cB = 0.f, tA = 1.f;
        #pragma unroll
        for (int s = 0; s < NW; ++s) {
            float4 v = pOut[s*64 + tid];
            cR = fmaf(tA, v.x, cR);
            cG = fmaf(tA, v.y, cG);
            cB = fmaf(tA, v.z, cB);
            tA *= v.w;
        }
        int p = row*IMW + xoff + tid;
        out[3*p+0] = cR; out[3*p+1] = cG; out[3*p+2] = cB;
    }
}

extern "C" void kernel_launch(void* const* d_in, const int* in_sizes, int n_in,
                              void* d_out, int out_size, void* d_ws, size_t ws_size,
                              hipStream_t stream)
{
    const float* means3D = (const float*)d_in[0];
    const float* covs3d  = (const float*)d_in[1];
    const float* colors  = (const float*)d_in[2];
    const float* opac    = (const float*)d_in[3];
    const float* Km      = (const float*)d_in[4];
    const float* Rm      = (const float*)d_in[5];
    const float* tv      = (const float*)d_in[6];

    float* sorted = (float*)d_ws;   // NGAUSS*12 floats = 96 KB

    preprank_kernel<<<NGAUSS, 64, 0, stream>>>(
        means3D, covs3d, colors, opac, Km, Rm, tv, sorted);

    size_t ldsBytes = 4*2048*sizeof(float)              // SoA cull arrays
                    + (size_t)2*NGAUSS*sizeof(float4)   // quads 1,2
                    + (size_t)NW*64*sizeof(float4);     // partials
    render_fused<<<NPIX/64, 1024, ldsBytes, stream>>>(sorted, (float*)d_out);
}